// Round 11
// baseline (126.454 us; speedup 1.0000x reference)
//
#include <hip/hip_runtime.h>
#include <hip/hip_bf16.h>

typedef unsigned short u16;
typedef short short8 __attribute__((ext_vector_type(8)));
typedef float f32x4 __attribute__((ext_vector_type(4)));
typedef unsigned short u16x4 __attribute__((ext_vector_type(4)));

#define BB 4
#define NS 512
#define EE 1024
#define HH 16
#define DD 64
#define MM (BB*NS)   // 2048
#define NSQ 4        // s-splits
#define SQW (NS/NSQ) // 128
#define NPR (SQW/32) // 4 chunks of 32 s per block

__device__ __forceinline__ u16 f2bfh(float x) {
  __hip_bfloat16 h = __float2bfloat16(x);
  union { __hip_bfloat16 h; u16 u; } c; c.h = h; return c.u;
}
__device__ __forceinline__ unsigned pkbf(float a, float b) {
  union { __hip_bfloat16 h; u16 u; } ca, cb;
  ca.h = __float2bfloat16(a); cb.h = __float2bfloat16(b);
  return (unsigned)ca.u | ((unsigned)cb.u << 16);
}
union S8 { short8 s; unsigned u[4]; };

__device__ __forceinline__ void gload_lds16(const void* g, void* l) {
  __builtin_amdgcn_global_load_lds(
      (const __attribute__((address_space(1))) unsigned int*)g,
      (__attribute__((address_space(3))) unsigned int*)l, 16, 0, 0);
}

// ---------------- converts ----------------

__global__ void cvt_inputs(const float* __restrict__ q, const float* __restrict__ k,
                           const float* __restrict__ v,
                           u16* __restrict__ qb, u16* __restrict__ kb, u16* __restrict__ vb) {
  size_t g = (size_t)blockIdx.x * 256 + threadIdx.x;
  size_t e = g << 3;
  int seg = (int)(e >> 21);
  size_t off = e & ((1u << 21) - 1);
  const float* src = seg == 0 ? q : (seg == 1 ? k : v);
  u16* dst = seg == 0 ? qb : (seg == 1 ? kb : vb);
  float4 f0 = *(const float4*)(src + off);
  float4 f1 = *(const float4*)(src + off + 4);
  S8 r;
  r.u[0] = pkbf(f0.x, f0.y); r.u[1] = pkbf(f0.z, f0.w);
  r.u[2] = pkbf(f1.x, f1.y); r.u[3] = pkbf(f1.z, f1.w);
  *(short8*)(dst + off) = r.s;
}

// z<4: transpose+convert big weights; z==4 (block 0,0 only): W2T + W3P
__global__ void cvt_w(const float* __restrict__ Wq, const float* __restrict__ Wk,
                      const float* __restrict__ Wv, const float* __restrict__ Wo,
                      const float* __restrict__ W2, const float* __restrict__ W3,
                      u16* __restrict__ WqT, u16* __restrict__ WkT,
                      u16* __restrict__ WvT, u16* __restrict__ WoT,
                      u16* __restrict__ W2T, u16* __restrict__ W3P) {
  int z = blockIdx.z;
  if (z == 4) {
    if (blockIdx.x || blockIdx.y) return;
    int tid = threadIdx.x;
    for (int i = tid; i < 4096; i += 256) {
      int n = i >> 6, k = i & 63;
      W2T[i] = f2bfh(W2[k * 64 + n]);
    }
    for (int i = tid; i < 1024; i += 256) {
      int h = i >> 6, rem = i & 63;
      int k2 = rem >> 5, gg = (rem >> 3) & 3, j = rem & 7;
      int c = (2 * k2 + (j >> 2)) * 16 + gg * 4 + (j & 3);
      W3P[i] = f2bfh(W3[c * 16 + h]);
    }
    return;
  }
  const float* W = z == 0 ? Wq : z == 1 ? Wk : z == 2 ? Wv : Wo;
  u16* WT = z == 0 ? WqT : z == 1 ? WkT : z == 2 ? WvT : WoT;
  int n0 = blockIdx.x << 5, k0 = blockIdx.y << 5;
  __shared__ float tile[32][33];
  int tx = threadIdx.x & 31, ty = threadIdx.x >> 5;
  #pragma unroll
  for (int i = 0; i < 4; ++i) {
    int r = (i << 3) + ty;
    tile[r][tx] = W[(size_t)(k0 + r) * EE + n0 + tx];
  }
  __syncthreads();
  #pragma unroll
  for (int i = 0; i < 4; ++i) {
    int r = (i << 3) + ty;
    WT[(size_t)(n0 + r) * EE + k0 + tx] = f2bfh(tile[tx][r]);
  }
}

// ---------------- hi / hj ----------------

__global__ void hi_hj_kernel(const float* __restrict__ se, const float* __restrict__ W1,
                             const float* __restrict__ b1,
                             float* __restrict__ hi, float* __restrict__ hj) {
  int tid = threadIdx.x;
  int row = blockIdx.x * 4 + (tid >> 6);
  int c = tid & 63;
  float ah = b1[c], aj = 0.f;
  #pragma unroll 8
  for (int k = 0; k < 64; ++k) {
    float s = se[row * 64 + k];
    ah += s * W1[k * 64 + c];
    aj += s * W1[(k + 64) * 64 + c];
  }
  hi[row * 64 + c] = ah;
  hj[row * 64 + c] = aj;
}

// ------- main GEMM; MODE 0: bf16 QK-fragment layout, 1: bf16 V-fragment, 2: f32 row-major

template <int MODE>
__device__ __forceinline__ void gemm_body(const u16* __restrict__ A, const u16* __restrict__ Bt,
                                          const float* __restrict__ bias, void* __restrict__ Cout) {
  __shared__ u16 As[128 * 32];
  __shared__ u16 Bs[128 * 32];
  const int tid = threadIdx.x, lane = tid & 63, wave = tid >> 6;
  const int m0 = blockIdx.x * 128, n0 = blockIdx.y * 128;
  const int wr = wave >> 1, wc = wave & 1;

  const f32x4 zero = {0.f, 0.f, 0.f, 0.f};
  f32x4 acc[4][4];
  #pragma unroll
  for (int i = 0; i < 4; ++i)
    #pragma unroll
    for (int j = 0; j < 4; ++j) acc[i][j] = zero;

  const int rA = lane >> 2;
  const int cA = (lane & 3) << 3;

  for (int kt = 0; kt < EE; kt += 32) {
    #pragma unroll
    for (int i = 0; i < 2; ++i) {
      int base = ((i << 2) + wave) << 9;
      int row = (base >> 5) + rA;
      gload_lds16(A  + (size_t)(m0 + row) * EE + kt + cA, As + base);
      gload_lds16(Bt + (size_t)(n0 + row) * EE + kt + cA, Bs + base);
    }
    __syncthreads();
    short8 af[4], bfr[4];
    #pragma unroll
    for (int mf = 0; mf < 4; ++mf) {
      int row = wr * 64 + mf * 16 + (lane & 15);
      af[mf] = *(const short8*)(As + row * 32 + ((lane >> 4) << 3));
    }
    #pragma unroll
    for (int nf = 0; nf < 4; ++nf) {
      int row = wc * 64 + nf * 16 + (lane & 15);
      bfr[nf] = *(const short8*)(Bs + row * 32 + ((lane >> 4) << 3));
    }
    #pragma unroll
    for (int mf = 0; mf < 4; ++mf)
      #pragma unroll
      for (int nf = 0; nf < 4; ++nf)
        acc[mf][nf] = __builtin_amdgcn_mfma_f32_16x16x32_bf16(af[mf], bfr[nf], acc[mf][nf], 0, 0, 0);
    __syncthreads();
  }

  #pragma unroll
  for (int mf = 0; mf < 4; ++mf) {
    #pragma unroll
    for (int nf = 0; nf < 4; ++nf) {
      int col = n0 + wc * 64 + nf * 16 + (lane & 15);
      float bv = bias[col];
      #pragma unroll
      for (int j = 0; j < 4; ++j) {
        int rowm = m0 + wr * 64 + mf * 16 + ((lane >> 4) << 2) + j;
        float v = acc[mf][nf][j] + bv;
        if (MODE == 2) {
          ((float*)Cout)[(size_t)rowm * EE + col] = v;
        } else {
          int bb = rowm >> 9, r = rowm & 511;
          int h = col >> 6, d = col & 63;
          size_t off;
          if (MODE == 0)   // [b][h][t16][kk][lane=g*16+tl][8]
            off = ((((size_t)bb * HH + h) * 32 + (r >> 4)) << 10) + ((size_t)(d >> 5) << 9)
                + ((size_t)((((d >> 3) & 3) << 4) + (r & 15)) << 3) + (d & 7);
          else             // [b][h][s32][nf][lane=g*16+sl][8]
            off = (((((size_t)bb * HH + h) * 16 + (r >> 5)) * 4 + (d >> 4)) << 9)
                + ((size_t)((((r >> 3) & 3) << 4) + (d & 15)) << 3) + (r & 7);
          ((u16*)Cout)[off] = f2bfh(v);
        }
      }
    }
  }
}

__global__ __launch_bounds__(256, 2) void gemm_proj(
    const u16* __restrict__ qb, const u16* __restrict__ kb, const u16* __restrict__ vb,
    const u16* __restrict__ WqT, const u16* __restrict__ WkT, const u16* __restrict__ WvT,
    const float* __restrict__ bq, const float* __restrict__ bk, const float* __restrict__ bv_,
    u16* __restrict__ qF, u16* __restrict__ kF, u16* __restrict__ vF) {
  int z = blockIdx.z;
  if (z == 0)      gemm_body<0>(qb, WqT, bq, qF);
  else if (z == 1) gemm_body<0>(kb, WkT, bk, kF);
  else             gemm_body<1>(vb, WvT, bv_, vF);
}

__global__ __launch_bounds__(256, 2) void gemm_final(
    const u16* __restrict__ A, const u16* __restrict__ WoT,
    const float* __restrict__ bo, float* __restrict__ C) {
  gemm_body<2>(A, WoT, bo, C);
}

// ------- fused CAB MLP + QK^T + online softmax + PV --------
// R8 body (104 VGPR: comp3 single-buffer, hj-dbuf, inline qF loads) with the
// R10 grid: dim3(8,64), x = b*2+(sq&1) -> XCD keeps one batch + two 128-s
// ranges; y = tt*2+(sq>>1) -> co-resident blocks share the Q-tile.
// VGPR must stay < 128 so TWO 8-wave blocks fit per CU (waves halve at 128).

__global__ __launch_bounds__(512, 2) void fused_cab_attn(
    const float* __restrict__ hi, const float* __restrict__ hj,
    const u16* __restrict__ W2T, const u16* __restrict__ W3P,
    const float* __restrict__ b2, const float* __restrict__ b3,
    const float* __restrict__ temps,
    const u16* __restrict__ qF, const u16* __restrict__ kF,
    const u16* __restrict__ vF,
    float* __restrict__ Opart, float* __restrict__ mlpart) {
  const int b = blockIdx.x >> 1, sqlo = blockIdx.x & 1;
  const int tt = blockIdx.y >> 1, sqhi = blockIdx.y & 1;
  const int sq = (sqhi << 1) | sqlo;
  const int t0 = tt << 4;
  const int tid = threadIdx.x, lane = tid & 63, wave = tid >> 6;   // wave 0..7
  const int g = lane >> 4, sl = lane & 15;

  __shared__ float hi_s[16][80];
  __shared__ float hj_s[2][32][65];
  __shared__ float b2_s[64], b3_s[16], tp_s[16];
  __shared__ float comp3[16 * 273];   // [h]*273 + [s]*17 + [t]  (single buffer)
  __shared__ u16 Pl[8][16][40];       // per-wave P staging

  if (tid < 256) {
    int r = tid >> 4, c4 = (tid & 15) << 2;
    float4 hv = *(const float4*)(hi + ((size_t)(b * NS + t0 + r) << 6) + c4);
    *(f32x4*)&hi_s[r][c4] = (f32x4){hv.x, hv.y, hv.z, hv.w};
  } else {
    int ix = tid - 256;
    if (ix < 64) b2_s[ix] = b2[ix];
    else if (ix < 80) b3_s[ix - 64] = b3[ix - 64];
    else if (ix < 96) tp_s[ix - 80] = temps[ix - 80];
  }

  // hj staging coordinates (512 threads cover 32 rows x 16 quad-cols)
  const int hr = tid >> 4, hc4 = (tid & 15) << 2;
  {
    float4 a = *(const float4*)(hj + ((size_t)(b * NS + sq * SQW + hr) << 6) + hc4);
    hj_s[0][hr][hc4 + 0] = a.x; hj_s[0][hr][hc4 + 1] = a.y;
    hj_s[0][hr][hc4 + 2] = a.z; hj_s[0][hr][hc4 + 3] = a.w;
  }

  const f32x4 zero = {0.f, 0.f, 0.f, 0.f};
  f32x4 acc[2][4];                    // [hh][nf]
  #pragma unroll
  for (int i = 0; i < 2; ++i)
    #pragma unroll
    for (int j = 0; j < 4; ++j) acc[i][j] = zero;
  float m_run[2] = {-3e38f, -3e38f};
  float l_run[2] = {0.f, 0.f};

  int cur = 0;
  for (int pr = 0; pr < NPR; ++pr) {
    const int s0p = sq * SQW + (pr << 5);
    __syncthreads();   // hj_s[cur] ready; prev comp3 reads done

    // issue next chunk's hj load early (latency hides under MLP+QK)
    float4 hjnx;
    const bool have = (pr + 1) < NPR;
    if (have)
      hjnx = *(const float4*)(hj + ((size_t)(b * NS + s0p + 32 + hr) << 6) + hc4);

    float vsc[2][2][4];   // [ta][hh][j]

    #pragma unroll
    for (int ta = 0; ta < 2; ++ta) {
      if (ta) __syncthreads();   // comp3(ta=0) reads done before overwrite
      // ---- MLP for this 16-s tile -> comp3 ----
      {
        float hjv[2][8];
        #pragma unroll
        for (int kk = 0; kk < 2; ++kk)
          #pragma unroll
          for (int j = 0; j < 8; ++j)
            hjv[kk][j] = hj_s[cur][(ta << 4) + sl][kk * 32 + (g << 3) + j];

        short8 w3f[2];
        #pragma unroll
        for (int k2 = 0; k2 < 2; ++k2)
          w3f[k2] = *(const short8*)(W3P + (sl << 6) + k2 * 32 + (g << 3));

        float b2v[4][4];
        #pragma unroll
        for (int mfc = 0; mfc < 4; ++mfc)
          #pragma unroll
          for (int jj = 0; jj < 4; ++jj)
            b2v[mfc][jj] = b2_s[mfc * 16 + (g << 2) + jj];

        #pragma unroll
        for (int q = 0; q < 2; ++q) {
          int tl = (wave << 1) + q;
          short8 xb[2];
          #pragma unroll
          for (int kk = 0; kk < 2; ++kk) {
            int c0 = kk * 32 + (g << 3);
            f32x4 h0 = *(const f32x4*)&hi_s[tl][c0];
            f32x4 h1 = *(const f32x4*)&hi_s[tl][c0 + 4];
            float x[8];
            #pragma unroll
            for (int j = 0; j < 4; ++j) {
              x[j]     = fmaxf(h0[j] + hjv[kk][j], 0.f);
              x[j + 4] = fmaxf(h1[j] + hjv[kk][j + 4], 0.f);
            }
            S8 r;
            r.u[0] = pkbf(x[0], x[1]); r.u[1] = pkbf(x[2], x[3]);
            r.u[2] = pkbf(x[4], x[5]); r.u[3] = pkbf(x[6], x[7]);
            xb[kk] = r.s;
          }
          f32x4 accY[4];
          #pragma unroll
          for (int i = 0; i < 4; ++i) accY[i] = zero;
          #pragma unroll
          for (int kk = 0; kk < 2; ++kk)
            #pragma unroll
            for (int mfc = 0; mfc < 4; ++mfc) {
              short8 w2 = *(const short8*)(W2T + ((mfc * 16 + sl) << 6) + kk * 32 + (g << 3));
              accY[mfc] = __builtin_amdgcn_mfma_f32_16x16x32_bf16(w2, xb[kk], accY[mfc], 0, 0, 0);
            }
          f32x4 compD = zero;
          #pragma unroll
          for (int k2 = 0; k2 < 2; ++k2) {
            float y[8];
            #pragma unroll
            for (int j = 0; j < 4; ++j) {
              y[j]     = fmaxf(accY[2 * k2][j]     + b2v[2 * k2][j],     0.f);
              y[j + 4] = fmaxf(accY[2 * k2 + 1][j] + b2v[2 * k2 + 1][j], 0.f);
            }
            S8 r;
            r.u[0] = pkbf(y[0], y[1]); r.u[1] = pkbf(y[2], y[3]);
            r.u[2] = pkbf(y[4], y[5]); r.u[3] = pkbf(y[6], y[7]);
            compD = __builtin_amdgcn_mfma_f32_16x16x32_bf16(w3f[k2], r.s, compD, 0, 0, 0);
          }
          #pragma unroll
          for (int jj = 0; jj < 4; ++jj) {
            int h = (g << 2) + jj;
            comp3[h * 273 + sl * 17 + tl] = (compD[jj] + b3_s[h]) * tp_s[h];
          }
        }
      }
      __syncthreads();   // comp3 ready
      // ---- QK^T (swapped) from fragment-linear qF/kF ----
      const int s16 = (sq << 3) + (pr << 1) + ta;
      #pragma unroll
      for (int hh = 0; hh < 2; ++hh) {
        int h = (wave << 1) + hh;
        const u16* qb_ = qF + ((((size_t)b * HH + h) * 32 + tt) << 10) + (lane << 3);
        const u16* kb_ = kF + ((((size_t)b * HH + h) * 32 + s16) << 10) + (lane << 3);
        f32x4 accS = zero;
        accS = __builtin_amdgcn_mfma_f32_16x16x32_bf16(*(const short8*)kb_, *(const short8*)qb_, accS, 0, 0, 0);
        accS = __builtin_amdgcn_mfma_f32_16x16x32_bf16(*(const short8*)(kb_ + 512), *(const short8*)(qb_ + 512), accS, 0, 0, 0);
        #pragma unroll
        for (int j = 0; j < 4; ++j)
          vsc[ta][hh][j] = accS[j] * 0.125f + comp3[h * 273 + ((g << 2) + j) * 17 + sl];
      }
    }

    // write next hj rows into the alternate buffer (visible after next top barrier)
    if (have) {
      hj_s[cur ^ 1][hr][hc4 + 0] = hjnx.x; hj_s[cur ^ 1][hr][hc4 + 1] = hjnx.y;
      hj_s[cur ^ 1][hr][hc4 + 2] = hjnx.z; hj_s[cur ^ 1][hr][hc4 + 3] = hjnx.w;
    }

    // ---- per-head online softmax + PV over the 32-s chunk ----
    #pragma unroll
    for (int hh = 0; hh < 2; ++hh) {
      int h = (wave << 1) + hh;
      float e[8];
      float mx = -3e38f;
      #pragma unroll
      for (int j = 0; j < 4; ++j)
        mx = fmaxf(mx, fmaxf(vsc[0][hh][j], vsc[1][hh][j]));
      mx = fmaxf(mx, __shfl_xor(mx, 16, 64));
      mx = fmaxf(mx, __shfl_xor(mx, 32, 64));
      float mnew = fmaxf(m_run[hh], mx);
      float c = __expf(m_run[hh] - mnew);
      m_run[hh] = mnew;
      #pragma unroll
      for (int ta = 0; ta < 2; ++ta)
        #pragma unroll
        for (int j = 0; j < 4; ++j)
          e[ta * 4 + j] = __expf(vsc[ta][hh][j] - mnew);
      float ps = ((e[0] + e[1]) + (e[2] + e[3])) + ((e[4] + e[5]) + (e[6] + e[7]));
      ps += __shfl_xor(ps, 16, 64);
      ps += __shfl_xor(ps, 32, 64);
      l_run[hh] = l_run[hh] * c + ps;

      uint2 wA; wA.x = pkbf(e[0], e[1]); wA.y = pkbf(e[2], e[3]);
      uint2 wB; wB.x = pkbf(e[4], e[5]); wB.y = pkbf(e[6], e[7]);
      *(uint2*)&Pl[wave][sl][(g << 2)]      = wA;
      *(uint2*)&Pl[wave][sl][16 + (g << 2)] = wB;
      short8 pf = *(const short8*)&Pl[wave][sl][(g << 3)];

      float cb[4];
      #pragma unroll
      for (int j = 0; j < 4; ++j) cb[j] = __shfl(c, (g << 2) + j, 64);

      const u16* vb0 = vF + (((((size_t)b * HH + h) * 16 + (sq << 2) + pr) * 4) << 9) + (lane << 3);
      #pragma unroll
      for (int nf = 0; nf < 4; ++nf) {
        #pragma unroll
        for (int j = 0; j < 4; ++j) acc[hh][nf][j] *= cb[j];
        short8 vv = *(const short8*)(vb0 + ((size_t)nf << 9));
        acc[hh][nf] = __builtin_amdgcn_mfma_f32_16x16x32_bf16(pf, vv, acc[hh][nf], 0, 0, 0);
      }
    }
    cur ^= 1;
  }

  // ---- store partials ----
  size_t obase = ((size_t)sq * MM + (size_t)b * NS + t0) * EE;
  #pragma unroll
  for (int hh = 0; hh < 2; ++hh) {
    int h = (wave << 1) + hh;
    #pragma unroll
    for (int nf = 0; nf < 4; ++nf)
      #pragma unroll
      for (int j = 0; j < 4; ++j)
        Opart[obase + (size_t)((g << 2) + j) * EE + (h << 6) + nf * 16 + sl] = acc[hh][nf][j];
  }
  if (g == 0) {
    #pragma unroll
    for (int hh = 0; hh < 2; ++hh) {
      int h = (wave << 1) + hh;
      size_t mlb = (((size_t)sq * MM + b * NS + t0 + sl) * HH + h) * 2;
      mlpart[mlb] = m_run[hh];
      mlpart[mlb + 1] = l_run[hh];
    }
  }
}

// ---------------- combine NSQ s-split partials -> bf16 attn_out ----------------

__global__ void combine_pv(const float* __restrict__ Opart, const float* __restrict__ mlpart,
                           u16* __restrict__ attn_out) {
  int row = blockIdx.x;
  int tid = threadIdx.x;
  int c4 = tid << 2;
  int h = c4 >> 6;
  float m[NSQ], l[NSQ];
  #pragma unroll
  for (int pq = 0; pq < NSQ; ++pq) {
    size_t mb = (((size_t)pq * MM + row) * HH + h) * 2;
    m[pq] = mlpart[mb]; l[pq] = mlpart[mb + 1];
  }
  float M = m[0];
  #pragma unroll
  for (int pq = 1; pq < NSQ; ++pq) M = fmaxf(M, m[pq]);
  float den = 0.f;
  f32x4 num = {0.f, 0.f, 0.f, 0.f};
  #pragma unroll
  for (int pq = 0; pq < NSQ; ++pq) {
    float w = __expf(m[pq] - M);
    den += w * l[pq];
    f32x4 o = *(const f32x4*)(Opart + ((size_t)pq * MM + row) * EE + c4);
    #pragma unroll
    for (int i = 0; i < 4; ++i) num[i] += w * o[i];
  }
  float r = 1.0f / den;
  u16x4 out;
  #pragma unroll
  for (int i = 0; i < 4; ++i) out[i] = f2bfh(num[i] * r);
  *(u16x4*)(attn_out + (size_t)row * EE + c4) = out;
}

// ---------------- launch ----------------

extern "C" void kernel_launch(void* const* d_in, const int* in_sizes, int n_in,
                              void* d_out, int out_size, void* d_ws, size_t ws_size,
                              hipStream_t stream) {
  const float* query = (const float*)d_in[0];
  const float* key   = (const float*)d_in[1];
  const float* value = (const float*)d_in[2];
  const float* se    = (const float*)d_in[3];
  const float* Wq = (const float*)d_in[4];  const float* bq = (const float*)d_in[5];
  const float* Wk = (const float*)d_in[6];  const float* bk = (const float*)d_in[7];
  const float* Wv = (const float*)d_in[8];  const float* bv = (const float*)d_in[9];
  const float* Wo = (const float*)d_in[10]; const float* bo = (const float*)d_in[11];
  const float* W1 = (const float*)d_in[12]; const float* b1 = (const float*)d_in[13];
  const float* W2 = (const float*)d_in[14]; const float* b2 = (const float*)d_in[15];
  const float* W3 = (const float*)d_in[16]; const float* b3 = (const float*)d_in[17];
  const float* temps = (const float*)d_in[18];

  char* p = (char*)d_ws;
  auto alloc = [&](size_t bytes) { char* r = p; p += (bytes + 255) & ~(size_t)255; return r; };
  u16* qb  = (u16*)alloc((size_t)MM * EE * 2);
  u16* kb  = (u16*)alloc((size_t)MM * EE * 2);
  u16* vb  = (u16*)alloc((size_t)MM * EE * 2);
  u16* WqT = (u16*)alloc((size_t)EE * EE * 2);
  u16* WkT = (u16*)alloc((size_t)EE * EE * 2);
  u16* WvT = (u16*)alloc((size_t)EE * EE * 2);
  u16* WoT = (u16*)alloc((size_t)EE * EE * 2);
  u16* W2T = (u16*)alloc(4096 * 2);
  u16* W3P = (u16*)alloc(1024 * 2);
  u16* qF  = (u16*)alloc((size_t)MM * EE * 2);
  u16* kF  = (u16*)alloc((size_t)MM * EE * 2);
  u16* vF  = (u16*)alloc((size_t)MM * EE * 2);
  float* hi = (float*)alloc((size_t)MM * 64 * 4);
  float* hj = (float*)alloc((size_t)MM * 64 * 4);
  float* Opart = (float*)alloc((size_t)NSQ * MM * EE * 4);   // 32 MB
  float* mlpart = (float*)alloc((size_t)NSQ * MM * HH * 2 * 4);
  u16* attn_out = (u16*)alloc((size_t)MM * EE * 2);
  (void)ws_size; (void)in_sizes; (void)n_in; (void)out_size;

  cvt_inputs<<<3072, 256, 0, stream>>>(query, key, value, qb, kb, vb);
  cvt_w<<<dim3(32, 32, 5), 256, 0, stream>>>(Wq, Wk, Wv, Wo, W2, W3,
                                             WqT, WkT, WvT, WoT, W2T, W3P);
  hi_hj_kernel<<<512, 256, 0, stream>>>(se, W1, b1, hi, hj);
  gemm_proj<<<dim3(16, 8, 3), 256, 0, stream>>>(qb, kb, vb, WqT, WkT, WvT, bq, bk, bv, qF, kF, vF);
  fused_cab_attn<<<dim3(8, 64, 1), 512, 0, stream>>>(hi, hj, W2T, W3P, b2, b3, temps,
                                                     qF, kF, vF, Opart, mlpart);
  combine_pv<<<MM, 256, 0, stream>>>(Opart, mlpart, attn_out);
  gemm_final<<<dim3(16, 8, 1), 256, 0, stream>>>(attn_out, WoT, bo, (float*)d_out);
}

// Round 12
// 114.935 us; speedup vs baseline: 1.1002x; 1.1002x over previous
//
#include <hip/hip_runtime.h>
#include <hip/hip_bf16.h>

typedef unsigned short u16;
typedef short short8 __attribute__((ext_vector_type(8)));
typedef float f32x4 __attribute__((ext_vector_type(4)));
typedef unsigned short u16x4 __attribute__((ext_vector_type(4)));

#define BB 4
#define NS 512
#define EE 1024
#define HH 16
#define DD 64
#define MM (BB*NS)   // 2048
#define NSQ 2        // s-splits
#define SQW (NS/NSQ) // 256

__device__ __forceinline__ u16 f2bfh(float x) {
  __hip_bfloat16 h = __float2bfloat16(x);
  union { __hip_bfloat16 h; u16 u; } c; c.h = h; return c.u;
}
__device__ __forceinline__ unsigned pkbf(float a, float b) {
  union { __hip_bfloat16 h; u16 u; } ca, cb;
  ca.h = __float2bfloat16(a); cb.h = __float2bfloat16(b);
  return (unsigned)ca.u | ((unsigned)cb.u << 16);
}
union S8 { short8 s; unsigned u[4]; };

__device__ __forceinline__ void gload_lds16(const void* g, void* l) {
  __builtin_amdgcn_global_load_lds(
      (const __attribute__((address_space(1))) unsigned int*)g,
      (__attribute__((address_space(3))) unsigned int*)l, 16, 0, 0);
}

// ---------------- converts (merged) ----------------
// z 0-3: transpose+convert big weights; z==4 (block 0,0): W2T+W3P;
// z 5-7: input fp32->bf16 converts (1024 blocks per plane, 8 elem/thread).

__global__ void cvt_w(const float* __restrict__ Wq, const float* __restrict__ Wk,
                      const float* __restrict__ Wv, const float* __restrict__ Wo,
                      const float* __restrict__ W2, const float* __restrict__ W3,
                      const float* __restrict__ q, const float* __restrict__ k,
                      const float* __restrict__ v,
                      u16* __restrict__ WqT, u16* __restrict__ WkT,
                      u16* __restrict__ WvT, u16* __restrict__ WoT,
                      u16* __restrict__ W2T, u16* __restrict__ W3P,
                      u16* __restrict__ qb, u16* __restrict__ kb, u16* __restrict__ vb) {
  int z = blockIdx.z;
  if (z >= 5) {
    int seg = z - 5;
    const float* src = seg == 0 ? q : (seg == 1 ? k : v);
    u16* dst = seg == 0 ? qb : (seg == 1 ? kb : vb);
    size_t flat = ((size_t)blockIdx.y * 32 + blockIdx.x) * 256 + threadIdx.x;
    size_t off = flat << 3;
    float4 f0 = *(const float4*)(src + off);
    float4 f1 = *(const float4*)(src + off + 4);
    S8 r;
    r.u[0] = pkbf(f0.x, f0.y); r.u[1] = pkbf(f0.z, f0.w);
    r.u[2] = pkbf(f1.x, f1.y); r.u[3] = pkbf(f1.z, f1.w);
    *(short8*)(dst + off) = r.s;
    return;
  }
  if (z == 4) {
    if (blockIdx.x || blockIdx.y) return;
    int tid = threadIdx.x;
    for (int i = tid; i < 4096; i += 256) {
      int n = i >> 6, kk = i & 63;
      W2T[i] = f2bfh(W2[kk * 64 + n]);
    }
    for (int i = tid; i < 1024; i += 256) {
      int h = i >> 6, rem = i & 63;
      int k2 = rem >> 5, gg = (rem >> 3) & 3, j = rem & 7;
      int c = (2 * k2 + (j >> 2)) * 16 + gg * 4 + (j & 3);
      W3P[i] = f2bfh(W3[c * 16 + h]);
    }
    return;
  }
  const float* W = z == 0 ? Wq : z == 1 ? Wk : z == 2 ? Wv : Wo;
  u16* WT = z == 0 ? WqT : z == 1 ? WkT : z == 2 ? WvT : WoT;
  int n0 = blockIdx.x << 5, k0 = blockIdx.y << 5;
  __shared__ float tile[32][33];
  int tx = threadIdx.x & 31, ty = threadIdx.x >> 5;
  #pragma unroll
  for (int i = 0; i < 4; ++i) {
    int r = (i << 3) + ty;
    tile[r][tx] = W[(size_t)(k0 + r) * EE + n0 + tx];
  }
  __syncthreads();
  #pragma unroll
  for (int i = 0; i < 4; ++i) {
    int r = (i << 3) + ty;
    WT[(size_t)(n0 + r) * EE + k0 + tx] = f2bfh(tile[tx][r]);
  }
}

// ---------------- hi / hj ----------------

__global__ void hi_hj_kernel(const float* __restrict__ se, const float* __restrict__ W1,
                             const float* __restrict__ b1,
                             float* __restrict__ hi, float* __restrict__ hj) {
  int tid = threadIdx.x;
  int row = blockIdx.x * 4 + (tid >> 6);
  int c = tid & 63;
  float ah = b1[c], aj = 0.f;
  #pragma unroll 8
  for (int k = 0; k < 64; ++k) {
    float s = se[row * 64 + k];
    ah += s * W1[k * 64 + c];
    aj += s * W1[(k + 64) * 64 + c];
  }
  hi[row * 64 + c] = ah;
  hj[row * 64 + c] = aj;
}

// ------- main GEMM; MODE 0: bf16 QK-fragment layout, 1: bf16 V-fragment

template <int MODE>
__device__ __forceinline__ void gemm_body(const u16* __restrict__ A, const u16* __restrict__ Bt,
                                          const float* __restrict__ bias, void* __restrict__ Cout) {
  __shared__ u16 As[128 * 32];
  __shared__ u16 Bs[128 * 32];
  const int tid = threadIdx.x, lane = tid & 63, wave = tid >> 6;
  const int m0 = blockIdx.x * 128, n0 = blockIdx.y * 128;
  const int wr = wave >> 1, wc = wave & 1;

  const f32x4 zero = {0.f, 0.f, 0.f, 0.f};
  f32x4 acc[4][4];
  #pragma unroll
  for (int i = 0; i < 4; ++i)
    #pragma unroll
    for (int j = 0; j < 4; ++j) acc[i][j] = zero;

  const int rA = lane >> 2;
  const int cA = (lane & 3) << 3;

  for (int kt = 0; kt < EE; kt += 32) {
    #pragma unroll
    for (int i = 0; i < 2; ++i) {
      int base = ((i << 2) + wave) << 9;
      int row = (base >> 5) + rA;
      gload_lds16(A  + (size_t)(m0 + row) * EE + kt + cA, As + base);
      gload_lds16(Bt + (size_t)(n0 + row) * EE + kt + cA, Bs + base);
    }
    __syncthreads();
    short8 af[4], bfr[4];
    #pragma unroll
    for (int mf = 0; mf < 4; ++mf) {
      int row = wr * 64 + mf * 16 + (lane & 15);
      af[mf] = *(const short8*)(As + row * 32 + ((lane >> 4) << 3));
    }
    #pragma unroll
    for (int nf = 0; nf < 4; ++nf) {
      int row = wc * 64 + nf * 16 + (lane & 15);
      bfr[nf] = *(const short8*)(Bs + row * 32 + ((lane >> 4) << 3));
    }
    #pragma unroll
    for (int mf = 0; mf < 4; ++mf)
      #pragma unroll
      for (int nf = 0; nf < 4; ++nf)
        acc[mf][nf] = __builtin_amdgcn_mfma_f32_16x16x32_bf16(af[mf], bfr[nf], acc[mf][nf], 0, 0, 0);
    __syncthreads();
  }

  #pragma unroll
  for (int mf = 0; mf < 4; ++mf) {
    #pragma unroll
    for (int nf = 0; nf < 4; ++nf) {
      int col = n0 + wc * 64 + nf * 16 + (lane & 15);
      float bv = bias[col];
      #pragma unroll
      for (int j = 0; j < 4; ++j) {
        int rowm = m0 + wr * 64 + mf * 16 + ((lane >> 4) << 2) + j;
        float v = acc[mf][nf][j] + bv;
        int bb = rowm >> 9, r = rowm & 511;
        int h = col >> 6, d = col & 63;
        size_t off;
        if (MODE == 0)   // [b][h][t16][kk][lane=g*16+tl][8]
          off = ((((size_t)bb * HH + h) * 32 + (r >> 4)) << 10) + ((size_t)(d >> 5) << 9)
              + ((size_t)((((d >> 3) & 3) << 4) + (r & 15)) << 3) + (d & 7);
        else             // [b][h][s32][nf][lane=g*16+sl][8]
          off = (((((size_t)bb * HH + h) * 16 + (r >> 5)) * 4 + (d >> 4)) << 9)
              + ((size_t)((((r >> 3) & 3) << 4) + (d & 15)) << 3) + (r & 7);
        ((u16*)Cout)[off] = f2bfh(v);
      }
    }
  }
}

__global__ __launch_bounds__(256, 2) void gemm_proj(
    const u16* __restrict__ qb, const u16* __restrict__ kb, const u16* __restrict__ vb,
    const u16* __restrict__ WqT, const u16* __restrict__ WkT, const u16* __restrict__ WvT,
    const float* __restrict__ bq, const float* __restrict__ bk, const float* __restrict__ bv_,
    u16* __restrict__ qF, u16* __restrict__ kF, u16* __restrict__ vF) {
  int z = blockIdx.z;
  if (z == 0)      gemm_body<0>(qb, WqT, bq, qF);
  else if (z == 1) gemm_body<0>(kb, WkT, bk, kF);
  else             gemm_body<1>(vb, WvT, bv_, vF);
}

// ------- final GEMM: 64x128 tiles, grid (32,8) = 256 blocks (all CUs busy) -------

__global__ __launch_bounds__(256, 2) void gemm_final64(
    const u16* __restrict__ A, const u16* __restrict__ Bt,
    const float* __restrict__ bias, float* __restrict__ C) {
  __shared__ u16 As[64 * 32];
  __shared__ u16 Bs[128 * 32];
  const int tid = threadIdx.x, lane = tid & 63, wave = tid >> 6;
  const int m0 = blockIdx.x * 64, n0 = blockIdx.y * 128;
  const int wr = wave >> 1, wc = wave & 1;   // wave owns 32x64

  const f32x4 zero = {0.f, 0.f, 0.f, 0.f};
  f32x4 acc[2][4];
  #pragma unroll
  for (int i = 0; i < 2; ++i)
    #pragma unroll
    for (int j = 0; j < 4; ++j) acc[i][j] = zero;

  const int rA = lane >> 2;
  const int cA = (lane & 3) << 3;

  for (int kt = 0; kt < EE; kt += 32) {
    {   // A: 64 rows = 4 chunks of 16; wave handles chunk 'wave'
      int base = wave << 9;
      int row = (wave << 4) + rA;
      gload_lds16(A + (size_t)(m0 + row) * EE + kt + cA, As + base);
    }
    #pragma unroll
    for (int i = 0; i < 2; ++i) {   // B: 128 rows = 8 chunks
      int base = ((i << 2) + wave) << 9;
      int row = (base >> 5) + rA;
      gload_lds16(Bt + (size_t)(n0 + row) * EE + kt + cA, Bs + base);
    }
    __syncthreads();
    short8 af[2], bfr[4];
    #pragma unroll
    for (int mf = 0; mf < 2; ++mf) {
      int row = wr * 32 + mf * 16 + (lane & 15);
      af[mf] = *(const short8*)(As + row * 32 + ((lane >> 4) << 3));
    }
    #pragma unroll
    for (int nf = 0; nf < 4; ++nf) {
      int row = wc * 64 + nf * 16 + (lane & 15);
      bfr[nf] = *(const short8*)(Bs + row * 32 + ((lane >> 4) << 3));
    }
    #pragma unroll
    for (int mf = 0; mf < 2; ++mf)
      #pragma unroll
      for (int nf = 0; nf < 4; ++nf)
        acc[mf][nf] = __builtin_amdgcn_mfma_f32_16x16x32_bf16(af[mf], bfr[nf], acc[mf][nf], 0, 0, 0);
    __syncthreads();
  }

  #pragma unroll
  for (int mf = 0; mf < 2; ++mf)
    #pragma unroll
    for (int nf = 0; nf < 4; ++nf) {
      int col = n0 + wc * 64 + nf * 16 + (lane & 15);
      float bv = bias[col];
      #pragma unroll
      for (int j = 0; j < 4; ++j) {
        int rowm = m0 + wr * 32 + mf * 16 + ((lane >> 4) << 2) + j;
        C[(size_t)rowm * EE + col] = acc[mf][nf][j] + bv;
      }
    }
}

// ------- fused CAB MLP + QK^T + online softmax + PV (R8 exact config) --------
// 512 threads = 8 waves; wave handles heads {2w, 2w+1}; block = (b,sq) x t16.
// grid dim3(8,32): x = b*2+sq -> linear id % 8 = x -> one (b,sq) slice per XCD.
// hj_s double-buffered: next pr's rows loaded to regs at pr top, written after QK.

__global__ __launch_bounds__(512, 2) void fused_cab_attn(
    const float* __restrict__ hi, const float* __restrict__ hj,
    const u16* __restrict__ W2T, const u16* __restrict__ W3P,
    const float* __restrict__ b2, const float* __restrict__ b3,
    const float* __restrict__ temps,
    const u16* __restrict__ qF, const u16* __restrict__ kF,
    const u16* __restrict__ vF,
    float* __restrict__ Opart, float* __restrict__ mlpart) {
  const int b = blockIdx.x >> 1, sq = blockIdx.x & 1, tt = blockIdx.y;
  const int t0 = tt << 4;
  const int tid = threadIdx.x, lane = tid & 63, wave = tid >> 6;   // wave 0..7
  const int g = lane >> 4, sl = lane & 15;

  __shared__ float hi_s[16][80];
  __shared__ float hj_s[2][32][65];
  __shared__ float b2_s[64], b3_s[16], tp_s[16];
  __shared__ float comp3[16 * 273];   // [h]*273 + [s]*17 + [t]
  __shared__ u16 Pl[8][16][40];       // per-wave P staging

  if (tid < 256) {
    int r = tid >> 4, c4 = (tid & 15) << 2;
    float4 hv = *(const float4*)(hi + ((size_t)(b * NS + t0 + r) << 6) + c4);
    *(f32x4*)&hi_s[r][c4] = (f32x4){hv.x, hv.y, hv.z, hv.w};
  } else {
    int ix = tid - 256;
    if (ix < 64) b2_s[ix] = b2[ix];
    else if (ix < 80) b3_s[ix - 64] = b3[ix - 64];
    else if (ix < 96) tp_s[ix - 80] = temps[ix - 80];
  }

  // hj staging coordinates (512 threads cover 32 rows x 16 quad-cols)
  const int hr = tid >> 4, hc4 = (tid & 15) << 2;
  {
    float4 a = *(const float4*)(hj + ((size_t)(b * NS + sq * SQW + hr) << 6) + hc4);
    hj_s[0][hr][hc4 + 0] = a.x; hj_s[0][hr][hc4 + 1] = a.y;
    hj_s[0][hr][hc4 + 2] = a.z; hj_s[0][hr][hc4 + 3] = a.w;
  }

  const f32x4 zero = {0.f, 0.f, 0.f, 0.f};
  f32x4 acc[2][4];                    // [hh][nf]
  #pragma unroll
  for (int i = 0; i < 2; ++i)
    #pragma unroll
    for (int j = 0; j < 4; ++j) acc[i][j] = zero;
  float m_run[2] = {-3e38f, -3e38f};
  float l_run[2] = {0.f, 0.f};

  int cur = 0;
  for (int pr = 0; pr < 8; ++pr) {
    const int s0p = sq * SQW + (pr << 5);
    __syncthreads();   // hj_s[cur] ready; prev comp3 reads done

    // issue next pr's hj load early (latency hides under MLP+QK)
    float4 hjnx;
    const bool have = (pr + 1) < 8;
    if (have)
      hjnx = *(const float4*)(hj + ((size_t)(b * NS + s0p + 32 + hr) << 6) + hc4);

    float vsc[2][2][4];   // [ta][hh][j]

    #pragma unroll
    for (int ta = 0; ta < 2; ++ta) {
      if (ta) __syncthreads();   // comp3(ta=0) reads done before overwrite
      // ---- MLP for this 16-s tile -> comp3 ----
      {
        float hjv[2][8];
        #pragma unroll
        for (int kk = 0; kk < 2; ++kk)
          #pragma unroll
          for (int j = 0; j < 8; ++j)
            hjv[kk][j] = hj_s[cur][(ta << 4) + sl][kk * 32 + (g << 3) + j];

        short8 w3f[2];
        #pragma unroll
        for (int k2 = 0; k2 < 2; ++k2)
          w3f[k2] = *(const short8*)(W3P + (sl << 6) + k2 * 32 + (g << 3));

        float b2v[4][4];
        #pragma unroll
        for (int mfc = 0; mfc < 4; ++mfc)
          #pragma unroll
          for (int jj = 0; jj < 4; ++jj)
            b2v[mfc][jj] = b2_s[mfc * 16 + (g << 2) + jj];

        #pragma unroll
        for (int q = 0; q < 2; ++q) {
          int tl = (wave << 1) + q;
          short8 xb[2];
          #pragma unroll
          for (int kk = 0; kk < 2; ++kk) {
            int c0 = kk * 32 + (g << 3);
            f32x4 h0 = *(const f32x4*)&hi_s[tl][c0];
            f32x4 h1 = *(const f32x4*)&hi_s[tl][c0 + 4];
            float x[8];
            #pragma unroll
            for (int j = 0; j < 4; ++j) {
              x[j]     = fmaxf(h0[j] + hjv[kk][j], 0.f);
              x[j + 4] = fmaxf(h1[j] + hjv[kk][j + 4], 0.f);
            }
            S8 r;
            r.u[0] = pkbf(x[0], x[1]); r.u[1] = pkbf(x[2], x[3]);
            r.u[2] = pkbf(x[4], x[5]); r.u[3] = pkbf(x[6], x[7]);
            xb[kk] = r.s;
          }
          f32x4 accY[4];
          #pragma unroll
          for (int i = 0; i < 4; ++i) accY[i] = zero;
          #pragma unroll
          for (int kk = 0; kk < 2; ++kk)
            #pragma unroll
            for (int mfc = 0; mfc < 4; ++mfc) {
              short8 w2 = *(const short8*)(W2T + ((mfc * 16 + sl) << 6) + kk * 32 + (g << 3));
              accY[mfc] = __builtin_amdgcn_mfma_f32_16x16x32_bf16(w2, xb[kk], accY[mfc], 0, 0, 0);
            }
          f32x4 compD = zero;
          #pragma unroll
          for (int k2 = 0; k2 < 2; ++k2) {
            float y[8];
            #pragma unroll
            for (int j = 0; j < 4; ++j) {
              y[j]     = fmaxf(accY[2 * k2][j]     + b2v[2 * k2][j],     0.f);
              y[j + 4] = fmaxf(accY[2 * k2 + 1][j] + b2v[2 * k2 + 1][j], 0.f);
            }
            S8 r;
            r.u[0] = pkbf(y[0], y[1]); r.u[1] = pkbf(y[2], y[3]);
            r.u[2] = pkbf(y[4], y[5]); r.u[3] = pkbf(y[6], y[7]);
            compD = __builtin_amdgcn_mfma_f32_16x16x32_bf16(w3f[k2], r.s, compD, 0, 0, 0);
          }
          #pragma unroll
          for (int jj = 0; jj < 4; ++jj) {
            int h = (g << 2) + jj;
            comp3[h * 273 + sl * 17 + tl] = (compD[jj] + b3_s[h]) * tp_s[h];
          }
        }
      }
      __syncthreads();   // comp3 ready
      // ---- QK^T (swapped) from fragment-linear qF/kF ----
      const int s16 = (sq << 4) + (pr << 1) + ta;
      #pragma unroll
      for (int hh = 0; hh < 2; ++hh) {
        int h = (wave << 1) + hh;
        const u16* qb_ = qF + ((((size_t)b * HH + h) * 32 + tt) << 10) + (lane << 3);
        const u16* kb_ = kF + ((((size_t)b * HH + h) * 32 + s16) << 10) + (lane << 3);
        f32x4 accS = zero;
        accS = __builtin_amdgcn_mfma_f32_16x16x32_bf16(*(const short8*)kb_, *(const short8*)qb_, accS, 0, 0, 0);
        accS = __builtin_amdgcn_mfma_f32_16x16x32_bf16(*(const short8*)(kb_ + 512), *(const short8*)(qb_ + 512), accS, 0, 0, 0);
        #pragma unroll
        for (int j = 0; j < 4; ++j)
          vsc[ta][hh][j] = accS[j] * 0.125f + comp3[h * 273 + ((g << 2) + j) * 17 + sl];
      }
    }

    // write next hj rows into the alternate buffer (visible after next top barrier)
    if (have) {
      hj_s[cur ^ 1][hr][hc4 + 0] = hjnx.x; hj_s[cur ^ 1][hr][hc4 + 1] = hjnx.y;
      hj_s[cur ^ 1][hr][hc4 + 2] = hjnx.z; hj_s[cur ^ 1][hr][hc4 + 3] = hjnx.w;
    }

    // ---- per-head online softmax + PV over the 32-s chunk ----
    #pragma unroll
    for (int hh = 0; hh < 2; ++hh) {
      int h = (wave << 1) + hh;
      float e[8];
      float mx = -3e38f;
      #pragma unroll
      for (int j = 0; j < 4; ++j)
        mx = fmaxf(mx, fmaxf(vsc[0][hh][j], vsc[1][hh][j]));
      mx = fmaxf(mx, __shfl_xor(mx, 16, 64));
      mx = fmaxf(mx, __shfl_xor(mx, 32, 64));
      float mnew = fmaxf(m_run[hh], mx);
      float c = __expf(m_run[hh] - mnew);
      m_run[hh] = mnew;
      #pragma unroll
      for (int ta = 0; ta < 2; ++ta)
        #pragma unroll
        for (int j = 0; j < 4; ++j)
          e[ta * 4 + j] = __expf(vsc[ta][hh][j] - mnew);
      float ps = ((e[0] + e[1]) + (e[2] + e[3])) + ((e[4] + e[5]) + (e[6] + e[7]));
      ps += __shfl_xor(ps, 16, 64);
      ps += __shfl_xor(ps, 32, 64);
      l_run[hh] = l_run[hh] * c + ps;

      uint2 wA; wA.x = pkbf(e[0], e[1]); wA.y = pkbf(e[2], e[3]);
      uint2 wB; wB.x = pkbf(e[4], e[5]); wB.y = pkbf(e[6], e[7]);
      *(uint2*)&Pl[wave][sl][(g << 2)]      = wA;
      *(uint2*)&Pl[wave][sl][16 + (g << 2)] = wB;
      short8 pf = *(const short8*)&Pl[wave][sl][(g << 3)];

      float cb[4];
      #pragma unroll
      for (int j = 0; j < 4; ++j) cb[j] = __shfl(c, (g << 2) + j, 64);

      const u16* vb0 = vF + (((((size_t)b * HH + h) * 16 + (sq << 3) + pr) * 4) << 9) + (lane << 3);
      #pragma unroll
      for (int nf = 0; nf < 4; ++nf) {
        #pragma unroll
        for (int j = 0; j < 4; ++j) acc[hh][nf][j] *= cb[j];
        short8 vv = *(const short8*)(vb0 + ((size_t)nf << 9));
        acc[hh][nf] = __builtin_amdgcn_mfma_f32_16x16x32_bf16(pf, vv, acc[hh][nf], 0, 0, 0);
      }
    }
    cur ^= 1;
  }

  // ---- store partials ----
  size_t obase = ((size_t)sq * MM + (size_t)b * NS + t0) * EE;
  #pragma unroll
  for (int hh = 0; hh < 2; ++hh) {
    int h = (wave << 1) + hh;
    #pragma unroll
    for (int nf = 0; nf < 4; ++nf)
      #pragma unroll
      for (int j = 0; j < 4; ++j)
        Opart[obase + (size_t)((g << 2) + j) * EE + (h << 6) + nf * 16 + sl] = acc[hh][nf][j];
  }
  if (g == 0) {
    #pragma unroll
    for (int hh = 0; hh < 2; ++hh) {
      int h = (wave << 1) + hh;
      size_t mlb = (((size_t)sq * MM + b * NS + t0 + sl) * HH + h) * 2;
      mlpart[mlb] = m_run[hh];
      mlpart[mlb + 1] = l_run[hh];
    }
  }
}

// ---------------- combine 2 s-half partials -> bf16 attn_out ----------------

__global__ void combine_pv(const float* __restrict__ Opart, const float* __restrict__ mlpart,
                           u16* __restrict__ attn_out) {
  int row = blockIdx.x;
  int tid = threadIdx.x;
  int c4 = tid << 2;
  int h = c4 >> 6;
  float m[NSQ], l[NSQ];
  #pragma unroll
  for (int pq = 0; pq < NSQ; ++pq) {
    size_t mb = (((size_t)pq * MM + row) * HH + h) * 2;
    m[pq] = mlpart[mb]; l[pq] = mlpart[mb + 1];
  }
  float M = m[0];
  #pragma unroll
  for (int pq = 1; pq < NSQ; ++pq) M = fmaxf(M, m[pq]);
  float den = 0.f;
  f32x4 num = {0.f, 0.f, 0.f, 0.f};
  #pragma unroll
  for (int pq = 0; pq < NSQ; ++pq) {
    float w = __expf(m[pq] - M);
    den += w * l[pq];
    f32x4 o = *(const f32x4*)(Opart + ((size_t)pq * MM + row) * EE + c4);
    #pragma unroll
    for (int i = 0; i < 4; ++i) num[i] += w * o[i];
  }
  float r = 1.0f / den;
  u16x4 out;
  #pragma unroll
  for (int i = 0; i < 4; ++i) out[i] = f2bfh(num[i] * r);
  *(u16x4*)(attn_out + (size_t)row * EE + c4) = out;
}

// ---------------- launch ----------------

extern "C" void kernel_launch(void* const* d_in, const int* in_sizes, int n_in,
                              void* d_out, int out_size, void* d_ws, size_t ws_size,
                              hipStream_t stream) {
  const float* query = (const float*)d_in[0];
  const float* key   = (const float*)d_in[1];
  const float* value = (const float*)d_in[2];
  const float* se    = (const float*)d_in[3];
  const float* Wq = (const float*)d_in[4];  const float* bq = (const float*)d_in[5];
  const float* Wk = (const float*)d_in[6];  const float* bk = (const float*)d_in[7];
  const float* Wv = (const float*)d_in[8];  const float* bv = (const float*)d_in[9];
  const float* Wo = (const float*)d_in[10]; const float* bo = (const float*)d_in[11];
  const float* W1 = (const float*)d_in[12]; const float* b1 = (const float*)d_in[13];
  const float* W2 = (const float*)d_in[14]; const float* b2 = (const float*)d_in[15];
  const float* W3 = (const float*)d_in[16]; const float* b3 = (const float*)d_in[17];
  const float* temps = (const float*)d_in[18];

  char* p = (char*)d_ws;
  auto alloc = [&](size_t bytes) { char* r = p; p += (bytes + 255) & ~(size_t)255; return r; };
  u16* qb  = (u16*)alloc((size_t)MM * EE * 2);
  u16* kb  = (u16*)alloc((size_t)MM * EE * 2);
  u16* vb  = (u16*)alloc((size_t)MM * EE * 2);
  u16* WqT = (u16*)alloc((size_t)EE * EE * 2);
  u16* WkT = (u16*)alloc((size_t)EE * EE * 2);
  u16* WvT = (u16*)alloc((size_t)EE * EE * 2);
  u16* WoT = (u16*)alloc((size_t)EE * EE * 2);
  u16* W2T = (u16*)alloc(4096 * 2);
  u16* W3P = (u16*)alloc(1024 * 2);
  u16* qF  = (u16*)alloc((size_t)MM * EE * 2);
  u16* kF  = (u16*)alloc((size_t)MM * EE * 2);
  u16* vF  = (u16*)alloc((size_t)MM * EE * 2);
  float* hi = (float*)alloc((size_t)MM * 64 * 4);
  float* hj = (float*)alloc((size_t)MM * 64 * 4);
  float* Opart = (float*)alloc((size_t)NSQ * MM * EE * 4);   // 16 MB
  float* mlpart = (float*)alloc((size_t)NSQ * MM * HH * 2 * 4);
  u16* attn_out = (u16*)alloc((size_t)MM * EE * 2);
  (void)ws_size; (void)in_sizes; (void)n_in; (void)out_size;

  cvt_w<<<dim3(32, 32, 8), 256, 0, stream>>>(Wq, Wk, Wv, Wo, W2, W3, query, key, value,
                                             WqT, WkT, WvT, WoT, W2T, W3P, qb, kb, vb);
  hi_hj_kernel<<<512, 256, 0, stream>>>(se, W1, b1, hi, hj);
  gemm_proj<<<dim3(16, 8, 3), 256, 0, stream>>>(qb, kb, vb, WqT, WkT, WvT, bq, bk, bv, qF, kF, vF);
  fused_cab_attn<<<dim3(8, 32, 1), 512, 0, stream>>>(hi, hj, W2T, W3P, b2, b3, temps,
                                                     qF, kF, vF, Opart, mlpart);
  combine_pv<<<MM, 256, 0, stream>>>(Opart, mlpart, attn_out);
  gemm_final64<<<dim3(32, 8), 256, 0, stream>>>(attn_out, WoT, bo, (float*)d_out);
}